// Round 8
// baseline (55.642 us; speedup 1.0000x reference)
//
#include <hip/hip_runtime.h>

// Problem constants (match reference)
#define N_VOCAB 50400
#define D_MODEL 4096
#define SHARDS  8
#define SEQ     2048
#define BATCH   4
#define VP      (N_VOCAB / SHARDS)   // 6300 rows per shard
#define TOKENS  (BATCH * SEQ)        // 8192
#define SPLIT   2                    // blocks per sequence position
#define DCHUNK  (D_MODEL / SPLIT)    // 2048 floats per block

typedef float f32x4 __attribute__((ext_vector_type(4)));

// Kernel A: combo[q][d] = sum(bias[:,d]) + sum_{sh<q} kernel[sh][VP-1][d]
//                                        + sum_{sh>q} kernel[sh][0][d]
__global__ __launch_bounds__(256) void combo_kernel(
        const float* __restrict__ kern,
        const float* __restrict__ bias,
        float* __restrict__ combo) {
    int d = blockIdx.x * blockDim.x + threadIdx.x;
    int q = blockIdx.y;
    float v = 0.f;
#pragma unroll
    for (int sh = 0; sh < SHARDS; ++sh)
        v += bias[sh * D_MODEL + d];
#pragma unroll
    for (int sh = 0; sh < SHARDS; ++sh) {
        if (sh != q) {
            size_t row = (size_t)sh * VP + (sh < q ? (VP - 1) : 0);
            v += kern[row * D_MODEL + d];
        }
    }
    combo[q * D_MODEL + d] = v;
}

// Kernel B: two blocks per sequence position s (each covers half of D_MODEL),
// all BATCH tokens sharing pos[s]. Cached loads (kern/pos/combo), NT stores
// (write stream must not evict read lines from L2). Phase 1 issues all 10
// HBM loads up front; halved in-flight state vs the full-row version ->
// ~70 VGPR -> more waves/SIMD to hide the ~900-cycle gather latency.
__global__ __launch_bounds__(256) void embed_kernel(
        const int*   __restrict__ x,
        const float* __restrict__ kern,
        const float* __restrict__ pos,    // viewed flat as [SEQ][D_MODEL]
        const float* __restrict__ combo,
        float*       __restrict__ out) {
    int bid  = blockIdx.x;
    int s    = bid >> 1;                  // sequence position
    int doff = (bid & 1) * (DCHUNK / 4);  // f32x4 offset of this half-row

    const f32x4* krow[BATCH];
    const f32x4* crow[BATCH];
    f32x4*       orow[BATCH];
#pragma unroll
    for (int b = 0; b < BATCH; ++b) {
        int xi = x[b * SEQ + s];
        unsigned q = (unsigned)xi / (unsigned)VP;
        int r = xi - (int)(q * VP);
        krow[b] = (const f32x4*)(kern  + ((size_t)q * VP + (size_t)r) * D_MODEL) + doff;
        crow[b] = (const f32x4*)(combo + (size_t)q * D_MODEL) + doff;
        orow[b] = (f32x4*)      (out   + ((size_t)b * SEQ + s) * D_MODEL) + doff;
    }
    const f32x4* prow = (const f32x4*)(pos + (size_t)s * D_MODEL) + doff;

    int tid = threadIdx.x;
    enum { NJ = DCHUNK / 4 / 256 };   // 2 chunks of 16 B/thread

    // Phase 1: issue every HBM load before any use.
    f32x4 p[NJ], k[BATCH][NJ];
#pragma unroll
    for (int j = 0; j < NJ; ++j)
        p[j] = prow[tid + j * 256];
#pragma unroll
    for (int b = 0; b < BATCH; ++b)
#pragma unroll
        for (int j = 0; j < NJ; ++j)
            k[b][j] = krow[b][tid + j * 256];

    // Phase 2: L2-hot combo read + add + NT store.
#pragma unroll
    for (int b = 0; b < BATCH; ++b)
#pragma unroll
        for (int j = 0; j < NJ; ++j) {
            int i = tid + j * 256;
            f32x4 o = k[b][j] + crow[b][i] + p[j];
            __builtin_nontemporal_store(o, &orow[b][i]);
        }
}

extern "C" void kernel_launch(void* const* d_in, const int* in_sizes, int n_in,
                              void* d_out, int out_size, void* d_ws, size_t ws_size,
                              hipStream_t stream) {
    const int*   x    = (const int*)  d_in[0];  // [BATCH, SEQ] int32
    const float* kern = (const float*)d_in[1];  // [SHARDS, VP, D_MODEL] f32
    const float* bias = (const float*)d_in[2];  // [SHARDS, D_MODEL] f32
    const float* pos  = (const float*)d_in[3];  // [SHARDS, SEQ, DP] f32 == flat [SEQ, D_MODEL]
    float* out   = (float*)d_out;               // [BATCH, SEQ, D_MODEL] f32
    float* combo = (float*)d_ws;                // 8 * 4096 f32 = 128 KB scratch

    combo_kernel<<<dim3(D_MODEL / 256, SHARDS), 256, 0, stream>>>(kern, bias, combo);
    embed_kernel<<<SEQ * SPLIT, 256, 0, stream>>>(x, kern, pos, combo, out);
}

// Round 9
// 53.665 us; speedup vs baseline: 1.0368x; 1.0368x over previous
//
#include <hip/hip_runtime.h>

// Problem constants (match reference)
#define N_VOCAB 50400
#define D_MODEL 4096
#define SHARDS  8
#define SEQ     2048
#define BATCH   4
#define VP      (N_VOCAB / SHARDS)   // 6300 rows per shard
#define TOKENS  (BATCH * SEQ)        // 8192

typedef float f32x4 __attribute__((ext_vector_type(4)));

// ---- Final configuration (measured best: 54.6 us) -------------------------
// Math: sharded one-hot matmul collapses to a row gather plus a per-shard-q
// correction table:
//   out[b,s] = kernel[q][x-q*VP] + combo[q] + pos_flat[s],
//   combo[q] = sum(bias) + sum_{sh<q} kernel[sh][VP-1] + sum_{sh>q} kernel[sh][0]
// Roofline: ~286 MB obligatory HBM traffic/replay (118 MB unique gather rows
// + 33.6 MB pos + 134 MB output). Embed runs at ~5.8-6.0 TB/s = ~93% of the
// 6.29 TB/s copy ceiling; read+write set (285 MB) exceeds the 268 MB L3 so
// cross-replay residency is not attainable (verified R6/R7 A/B).
// ----------------------------------------------------------------------------

// Kernel A: combo table, 8 x 4096 f32 in d_ws. 128 blocks, coalesced.
__global__ __launch_bounds__(256) void combo_kernel(
        const float* __restrict__ kern,
        const float* __restrict__ bias,
        float* __restrict__ combo) {
    int d = blockIdx.x * blockDim.x + threadIdx.x;
    int q = blockIdx.y;
    float v = 0.f;
#pragma unroll
    for (int sh = 0; sh < SHARDS; ++sh)
        v += bias[sh * D_MODEL + d];
#pragma unroll
    for (int sh = 0; sh < SHARDS; ++sh) {
        if (sh != q) {
            size_t row = (size_t)sh * VP + (sh < q ? (VP - 1) : 0);
            v += kern[row * D_MODEL + d];
        }
    }
    combo[q * D_MODEL + d] = v;
}

// Kernel B: one block per sequence position s, all BATCH tokens sharing
// pos[s] (pos read from HBM exactly once overall). Cached loads for the
// gather/pos (L2 reuse of duplicate rows), NONTEMPORAL stores for the
// write-only output (keeps the write stream from evicting read lines).
// Phase 1 issues all 20 HBM loads before any use (max bytes in flight);
// phase 2 adds the L2-hot combo rows and stores.
__global__ __launch_bounds__(256) void embed_kernel(
        const int*   __restrict__ x,
        const float* __restrict__ kern,
        const float* __restrict__ pos,    // viewed flat as [SEQ][D_MODEL]
        const float* __restrict__ combo,
        float*       __restrict__ out) {
    int s = blockIdx.x;            // sequence position in [0, SEQ)

    const f32x4* krow[BATCH];
    const f32x4* crow[BATCH];
    f32x4*       orow[BATCH];
#pragma unroll
    for (int b = 0; b < BATCH; ++b) {
        int xi = x[b * SEQ + s];
        unsigned q = (unsigned)xi / (unsigned)VP;
        int r = xi - (int)(q * VP);
        krow[b] = (const f32x4*)(kern  + ((size_t)q * VP + (size_t)r) * D_MODEL);
        crow[b] = (const f32x4*)(combo + (size_t)q * D_MODEL);
        orow[b] = (f32x4*)      (out   + ((size_t)b * SEQ + s) * D_MODEL);
    }
    const f32x4* prow = (const f32x4*)(pos + (size_t)s * D_MODEL);

    int tid = threadIdx.x;
    enum { NJ = D_MODEL / 4 / 256 };   // 4 chunks of 16 B/thread

    // Phase 1: issue every HBM load before any use.
    f32x4 p[NJ], k[BATCH][NJ];
#pragma unroll
    for (int j = 0; j < NJ; ++j)
        p[j] = prow[tid + j * 256];
#pragma unroll
    for (int b = 0; b < BATCH; ++b)
#pragma unroll
        for (int j = 0; j < NJ; ++j)
            k[b][j] = krow[b][tid + j * 256];

    // Phase 2: L2-hot combo read + add + NT store.
#pragma unroll
    for (int b = 0; b < BATCH; ++b)
#pragma unroll
        for (int j = 0; j < NJ; ++j) {
            int i = tid + j * 256;
            f32x4 o = k[b][j] + crow[b][i] + p[j];
            __builtin_nontemporal_store(o, &orow[b][i]);
        }
}

extern "C" void kernel_launch(void* const* d_in, const int* in_sizes, int n_in,
                              void* d_out, int out_size, void* d_ws, size_t ws_size,
                              hipStream_t stream) {
    const int*   x    = (const int*)  d_in[0];  // [BATCH, SEQ] int32
    const float* kern = (const float*)d_in[1];  // [SHARDS, VP, D_MODEL] f32
    const float* bias = (const float*)d_in[2];  // [SHARDS, D_MODEL] f32
    const float* pos  = (const float*)d_in[3];  // [SHARDS, SEQ, DP] f32 == flat [SEQ, D_MODEL]
    float* out   = (float*)d_out;               // [BATCH, SEQ, D_MODEL] f32
    float* combo = (float*)d_ws;                // 8 * 4096 f32 = 128 KB scratch

    combo_kernel<<<dim3(D_MODEL / 256, SHARDS), 256, 0, stream>>>(kern, bias, combo);
    embed_kernel<<<SEQ, 256, 0, stream>>>(x, kern, pos, combo, out);
}